// Round 1
// baseline (146.050 us; speedup 1.0000x reference)
//
#include <hip/hip_runtime.h>

#define T_LEN 16384
#define VAR_EPS 1e-5f

// ---------------------------------------------------------------------------
// Stage 1: ONE block per row, 256 threads. Each thread consumes 16 float4 per
// stream (4096 float4 per stream per row), in 4 chunks of 4, double-buffered
// (A/B register sets) so ~8 loads stay in flight while the previous chunk is
// reduced. Full in-block reduction -> per-row loss written non-atomically.
// No atomics => no workspace memset node needed.
// ---------------------------------------------------------------------------

#define LOAD8(P0,P1,P2,P3,Q0,Q1,Q2,Q3,BASE)        \
    P0 = p4[(BASE) + tid];                          \
    P1 = p4[(BASE) + tid + 256];                    \
    P2 = p4[(BASE) + tid + 512];                    \
    P3 = p4[(BASE) + tid + 768];                    \
    Q0 = t4[(BASE) + tid];                          \
    Q1 = t4[(BASE) + tid + 256];                    \
    Q2 = t4[(BASE) + tid + 512];                    \
    Q3 = t4[(BASE) + tid + 768];

#define ACC8(P0,P1,P2,P3,Q0,Q1,Q2,Q3)                                        \
    sp  += (P0.x + P0.y + P0.z + P0.w) + (P1.x + P1.y + P1.z + P1.w)         \
         + (P2.x + P2.y + P2.z + P2.w) + (P3.x + P3.y + P3.z + P3.w);        \
    st  += (Q0.x + Q0.y + Q0.z + Q0.w) + (Q1.x + Q1.y + Q1.z + Q1.w)         \
         + (Q2.x + Q2.y + Q2.z + Q2.w) + (Q3.x + Q3.y + Q3.z + Q3.w);        \
    spp += P0.x*P0.x + P0.y*P0.y + P0.z*P0.z + P0.w*P0.w                     \
         + P1.x*P1.x + P1.y*P1.y + P1.z*P1.z + P1.w*P1.w                     \
         + P2.x*P2.x + P2.y*P2.y + P2.z*P2.z + P2.w*P2.w                     \
         + P3.x*P3.x + P3.y*P3.y + P3.z*P3.z + P3.w*P3.w;                    \
    stt += Q0.x*Q0.x + Q0.y*Q0.y + Q0.z*Q0.z + Q0.w*Q0.w                     \
         + Q1.x*Q1.x + Q1.y*Q1.y + Q1.z*Q1.z + Q1.w*Q1.w                     \
         + Q2.x*Q2.x + Q2.y*Q2.y + Q2.z*Q2.z + Q2.w*Q2.w                     \
         + Q3.x*Q3.x + Q3.y*Q3.y + Q3.z*Q3.z + Q3.w*Q3.w;                    \
    spt += P0.x*Q0.x + P0.y*Q0.y + P0.z*Q0.z + P0.w*Q0.w                     \
         + P1.x*Q1.x + P1.y*Q1.y + P1.z*Q1.z + P1.w*Q1.w                     \
         + P2.x*Q2.x + P2.y*Q2.y + P2.z*Q2.z + P2.w*Q2.w                     \
         + P3.x*Q3.x + P3.y*Q3.y + P3.z*Q3.z + P3.w*Q3.w;

__global__ __launch_bounds__(256) void pearson_row_kernel(
    const float* __restrict__ pred, const float* __restrict__ target,
    float* __restrict__ loss)
{
    const int row = blockIdx.x;
    const int tid = threadIdx.x;

    const float4* __restrict__ p4 = (const float4*)(pred   + (size_t)row * T_LEN);
    const float4* __restrict__ t4 = (const float4*)(target + (size_t)row * T_LEN);

    float sp = 0.f, st = 0.f, spp = 0.f, stt = 0.f, spt = 0.f;

    float4 pa0, pa1, pa2, pa3, ta0, ta1, ta2, ta3;   // buffer A
    float4 pb0, pb1, pb2, pb3, tb0, tb1, tb2, tb3;   // buffer B

    // Software pipeline: load A, load B, acc A, load A', acc B, load B',
    // acc A', acc B'.  Keeps ~8 dwordx4 loads outstanding in steady state.
    LOAD8(pa0, pa1, pa2, pa3, ta0, ta1, ta2, ta3, 0)
    LOAD8(pb0, pb1, pb2, pb3, tb0, tb1, tb2, tb3, 1024)
    ACC8 (pa0, pa1, pa2, pa3, ta0, ta1, ta2, ta3)
    LOAD8(pa0, pa1, pa2, pa3, ta0, ta1, ta2, ta3, 2048)
    ACC8 (pb0, pb1, pb2, pb3, tb0, tb1, tb2, tb3)
    LOAD8(pb0, pb1, pb2, pb3, tb0, tb1, tb2, tb3, 3072)
    ACC8 (pa0, pa1, pa2, pa3, ta0, ta1, ta2, ta3)
    ACC8 (pb0, pb1, pb2, pb3, tb0, tb1, tb2, tb3)

    // 64-lane wave reduction (5 moments).
    #pragma unroll
    for (int off = 32; off > 0; off >>= 1) {
        sp  += __shfl_down(sp,  off);
        st  += __shfl_down(st,  off);
        spp += __shfl_down(spp, off);
        stt += __shfl_down(stt, off);
        spt += __shfl_down(spt, off);
    }

    // Cross-wave combine (4 waves) via LDS.
    __shared__ float ws[4][8];
    const int wid = tid >> 6;
    if ((tid & 63) == 0) {
        ws[wid][0] = sp;  ws[wid][1] = st;  ws[wid][2] = spp;
        ws[wid][3] = stt; ws[wid][4] = spt;
    }
    __syncthreads();

    if (tid == 0) {
        float S_p  = ws[0][0] + ws[1][0] + ws[2][0] + ws[3][0];
        float S_t  = ws[0][1] + ws[1][1] + ws[2][1] + ws[3][1];
        float S_pp = ws[0][2] + ws[1][2] + ws[2][2] + ws[3][2];
        float S_tt = ws[0][3] + ws[1][3] + ws[2][3] + ws[3][3];
        float S_pt = ws[0][4] + ws[1][4] + ws[2][4] + ws[3][4];

        const float T   = (float)T_LEN;
        const float inv = 1.0f / T;
        float cp2 = S_pp - S_p * S_p * inv;
        float ct2 = S_tt - S_t * S_t * inv;
        float num = S_pt - S_p * S_t * inv;

        float var_p = cp2 / (T - 1.0f);
        float var_t = ct2 / (T - 1.0f);
        float denom = sqrtf(cp2 * ct2);
        float safe  = (denom > 0.0f) ? denom : 1.0f;
        float corr  = num / safe;
        bool valid = (var_p > VAR_EPS) && (var_t > VAR_EPS) &&
                     (denom > 0.0f) && !isnan(corr);
        loss[row] = valid ? (1.0f - corr) : 1.0f;
    }
}

// ---------------------------------------------------------------------------
// Stage 2: one block, 256 threads, reduce B per-row losses -> mean (4 KB read).
// ---------------------------------------------------------------------------
__global__ __launch_bounds__(256) void pearson_mean_kernel(
    const float* __restrict__ loss, float* __restrict__ out, int B)
{
    const int tid = threadIdx.x;
    float s = 0.f;
    for (int r = tid; r < B; r += 256) s += loss[r];

    #pragma unroll
    for (int off = 32; off > 0; off >>= 1)
        s += __shfl_down(s, off);

    __shared__ float ws[4];
    if ((tid & 63) == 0) ws[tid >> 6] = s;
    __syncthreads();

    if (tid == 0)
        out[0] = (ws[0] + ws[1] + ws[2] + ws[3]) / (float)B;
}

extern "C" void kernel_launch(void* const* d_in, const int* in_sizes, int n_in,
                              void* d_out, int out_size, void* d_ws, size_t ws_size,
                              hipStream_t stream) {
    const float* pred   = (const float*)d_in[0];
    const float* target = (const float*)d_in[1];
    float* out  = (float*)d_out;
    float* lossbuf = (float*)d_ws;              // B floats, fully overwritten

    const int B = in_sizes[0] / T_LEN;

    // 2 graph nodes (was 3): no memset needed since stage 1 has no atomics
    // and overwrites every loss slot.
    pearson_row_kernel<<<B, 256, 0, stream>>>(pred, target, lossbuf);
    pearson_mean_kernel<<<1, 256, 0, stream>>>(lossbuf, out, B);
}

// Round 2
// 136.297 us; speedup vs baseline: 1.0716x; 1.0716x over previous
//
#include <hip/hip_runtime.h>

#define T_LEN 16384
#define VAR_EPS 1e-5f

// ext_vector float4 so __builtin_nontemporal_load lowers to
// global_load_dwordx4 with the nt cache-policy bit (stream past L1).
typedef float v4 __attribute__((ext_vector_type(4)));

#define NTL(P) __builtin_nontemporal_load(P)

// ---------------------------------------------------------------------------
// Stage 1: one block per row, 512 threads (8 waves). Each thread consumes
// 8 float4 per stream in 2 chunks of 4, double-buffered so ~8-16 dwordx4
// stay in flight. All loads nontemporal: data is touched exactly once, so
// L1 allocation is pure overhead and (theory) the L1 miss queue is the
// current ~3 TB/s wall.
// ---------------------------------------------------------------------------

#define LOAD8(P0,P1,P2,P3,Q0,Q1,Q2,Q3,BASE)        \
    P0 = NTL(p4 + (BASE) + tid);                    \
    P1 = NTL(p4 + (BASE) + tid + 512);              \
    P2 = NTL(p4 + (BASE) + tid + 1024);             \
    P3 = NTL(p4 + (BASE) + tid + 1536);             \
    Q0 = NTL(t4 + (BASE) + tid);                    \
    Q1 = NTL(t4 + (BASE) + tid + 512);              \
    Q2 = NTL(t4 + (BASE) + tid + 1024);             \
    Q3 = NTL(t4 + (BASE) + tid + 1536);

#define ACC8(P0,P1,P2,P3,Q0,Q1,Q2,Q3)                                        \
    sp  += (P0.x + P0.y + P0.z + P0.w) + (P1.x + P1.y + P1.z + P1.w)         \
         + (P2.x + P2.y + P2.z + P2.w) + (P3.x + P3.y + P3.z + P3.w);        \
    st  += (Q0.x + Q0.y + Q0.z + Q0.w) + (Q1.x + Q1.y + Q1.z + Q1.w)         \
         + (Q2.x + Q2.y + Q2.z + Q2.w) + (Q3.x + Q3.y + Q3.z + Q3.w);        \
    spp += P0.x*P0.x + P0.y*P0.y + P0.z*P0.z + P0.w*P0.w                     \
         + P1.x*P1.x + P1.y*P1.y + P1.z*P1.z + P1.w*P1.w                     \
         + P2.x*P2.x + P2.y*P2.y + P2.z*P2.z + P2.w*P2.w                     \
         + P3.x*P3.x + P3.y*P3.y + P3.z*P3.z + P3.w*P3.w;                    \
    stt += Q0.x*Q0.x + Q0.y*Q0.y + Q0.z*Q0.z + Q0.w*Q0.w                     \
         + Q1.x*Q1.x + Q1.y*Q1.y + Q1.z*Q1.z + Q1.w*Q1.w                     \
         + Q2.x*Q2.x + Q2.y*Q2.y + Q2.z*Q2.z + Q2.w*Q2.w                     \
         + Q3.x*Q3.x + Q3.y*Q3.y + Q3.z*Q3.z + Q3.w*Q3.w;                    \
    spt += P0.x*Q0.x + P0.y*Q0.y + P0.z*Q0.z + P0.w*Q0.w                     \
         + P1.x*Q1.x + P1.y*Q1.y + P1.z*Q1.z + P1.w*Q1.w                     \
         + P2.x*Q2.x + P2.y*Q2.y + P2.z*Q2.z + P2.w*Q2.w                     \
         + P3.x*Q3.x + P3.y*Q3.y + P3.z*Q3.z + P3.w*Q3.w;

__global__ __launch_bounds__(512) void pearson_row_kernel(
    const float* __restrict__ pred, const float* __restrict__ target,
    float* __restrict__ loss)
{
    const int row = blockIdx.x;
    const int tid = threadIdx.x;

    const v4* __restrict__ p4 = (const v4*)(pred   + (size_t)row * T_LEN);
    const v4* __restrict__ t4 = (const v4*)(target + (size_t)row * T_LEN);

    float sp = 0.f, st = 0.f, spp = 0.f, stt = 0.f, spt = 0.f;

    v4 pa0, pa1, pa2, pa3, ta0, ta1, ta2, ta3;   // buffer A
    v4 pb0, pb1, pb2, pb3, tb0, tb1, tb2, tb3;   // buffer B

    // 4096 float4 per stream / 512 threads = 8 per thread, 2 chunks of 4.
    LOAD8(pa0, pa1, pa2, pa3, ta0, ta1, ta2, ta3, 0)
    LOAD8(pb0, pb1, pb2, pb3, tb0, tb1, tb2, tb3, 2048)
    ACC8 (pa0, pa1, pa2, pa3, ta0, ta1, ta2, ta3)
    ACC8 (pb0, pb1, pb2, pb3, tb0, tb1, tb2, tb3)

    // 64-lane wave reduction (5 moments).
    #pragma unroll
    for (int off = 32; off > 0; off >>= 1) {
        sp  += __shfl_down(sp,  off);
        st  += __shfl_down(st,  off);
        spp += __shfl_down(spp, off);
        stt += __shfl_down(stt, off);
        spt += __shfl_down(spt, off);
    }

    // Cross-wave combine (8 waves) via LDS.
    __shared__ float ws[8][8];
    const int wid = tid >> 6;
    if ((tid & 63) == 0) {
        ws[wid][0] = sp;  ws[wid][1] = st;  ws[wid][2] = spp;
        ws[wid][3] = stt; ws[wid][4] = spt;
    }
    __syncthreads();

    if (tid == 0) {
        float S_p = 0.f, S_t = 0.f, S_pp = 0.f, S_tt = 0.f, S_pt = 0.f;
        #pragma unroll
        for (int w = 0; w < 8; ++w) {
            S_p  += ws[w][0];
            S_t  += ws[w][1];
            S_pp += ws[w][2];
            S_tt += ws[w][3];
            S_pt += ws[w][4];
        }

        const float T   = (float)T_LEN;
        const float inv = 1.0f / T;
        float cp2 = S_pp - S_p * S_p * inv;
        float ct2 = S_tt - S_t * S_t * inv;
        float num = S_pt - S_p * S_t * inv;

        float var_p = cp2 / (T - 1.0f);
        float var_t = ct2 / (T - 1.0f);
        float denom = sqrtf(cp2 * ct2);
        float safe  = (denom > 0.0f) ? denom : 1.0f;
        float corr  = num / safe;
        bool valid = (var_p > VAR_EPS) && (var_t > VAR_EPS) &&
                     (denom > 0.0f) && !isnan(corr);
        loss[row] = valid ? (1.0f - corr) : 1.0f;
    }
}

// ---------------------------------------------------------------------------
// Stage 2: one block, 256 threads, reduce B per-row losses -> mean (4 KB read).
// ---------------------------------------------------------------------------
__global__ __launch_bounds__(256) void pearson_mean_kernel(
    const float* __restrict__ loss, float* __restrict__ out, int B)
{
    const int tid = threadIdx.x;
    float s = 0.f;
    for (int r = tid; r < B; r += 256) s += loss[r];

    #pragma unroll
    for (int off = 32; off > 0; off >>= 1)
        s += __shfl_down(s, off);

    __shared__ float ws[4];
    if ((tid & 63) == 0) ws[tid >> 6] = s;
    __syncthreads();

    if (tid == 0)
        out[0] = (ws[0] + ws[1] + ws[2] + ws[3]) / (float)B;
}

extern "C" void kernel_launch(void* const* d_in, const int* in_sizes, int n_in,
                              void* d_out, int out_size, void* d_ws, size_t ws_size,
                              hipStream_t stream) {
    const float* pred   = (const float*)d_in[0];
    const float* target = (const float*)d_in[1];
    float* out  = (float*)d_out;
    float* lossbuf = (float*)d_ws;              // B floats, fully overwritten

    const int B = in_sizes[0] / T_LEN;

    pearson_row_kernel<<<B, 512, 0, stream>>>(pred, target, lossbuf);
    pearson_mean_kernel<<<1, 256, 0, stream>>>(lossbuf, out, B);
}